// Round 1
// baseline (497.094 us; speedup 1.0000x reference)
//
#include <hip/hip_runtime.h>
#include <hip/hip_bf16.h>
#include <math.h>

constexpr int B = 8, N = 4096, M = 2048, DIN = 256, DOUT = 128;
constexpr float SCORE_SCALE = 0.0625f; // 1/sqrt(DIN=256)

// ---------------- Kernel 1: gather + QKV projection ----------------
// One block = 8 consecutive (b,m) rows. g rows staged in LDS; each thread owns
// one output column e, accumulates q/k/v for all 8 rows.
__global__ __launch_bounds__(128) void k_proj(
    const float* __restrict__ Y, const int* __restrict__ idx,
    const float* __restrict__ Wq, const float* __restrict__ bq,
    const float* __restrict__ Wk, const float* __restrict__ bk,
    const float* __restrict__ Wv, const float* __restrict__ bv,
    float* __restrict__ Q, float* __restrict__ K, float* __restrict__ V)
{
    constexpr int TM = 8;
    __shared__ float g[TM][DIN];
    const int rm0 = blockIdx.x * TM;        // flat row b*M+m
    const int b = rm0 / M;
    const int t = threadIdx.x;              // 0..127 = output column e
    #pragma unroll
    for (int r = 0; r < TM; ++r) {
        const int id = idx[rm0 + r];
        const float2* src = (const float2*)(Y + ((size_t)b * N + id) * DIN);
        ((float2*)g[r])[t] = src[t];
    }
    __syncthreads();

    float aq[TM], ak[TM], av[TM];
    #pragma unroll
    for (int r = 0; r < TM; ++r) { aq[r] = 0.f; ak[r] = 0.f; av[r] = 0.f; }

    for (int d = 0; d < DIN; d += 4) {
        float wq[4], wk[4], wv[4];
        #pragma unroll
        for (int u = 0; u < 4; ++u) {
            wq[u] = Wq[(d + u) * DOUT + t];
            wk[u] = Wk[(d + u) * DOUT + t];
            wv[u] = Wv[(d + u) * DOUT + t];
        }
        #pragma unroll
        for (int r = 0; r < TM; ++r) {
            const float4 gv = *(const float4*)&g[r][d];
            aq[r] = fmaf(gv.x, wq[0], fmaf(gv.y, wq[1], fmaf(gv.z, wq[2], fmaf(gv.w, wq[3], aq[r]))));
            ak[r] = fmaf(gv.x, wk[0], fmaf(gv.y, wk[1], fmaf(gv.z, wk[2], fmaf(gv.w, wk[3], ak[r]))));
            av[r] = fmaf(gv.x, wv[0], fmaf(gv.y, wv[1], fmaf(gv.z, wv[2], fmaf(gv.w, wv[3], av[r]))));
        }
    }
    #pragma unroll
    for (int r = 0; r < TM; ++r) {
        const size_t o = (size_t)(rm0 + r) * DOUT + t;
        Q[o] = aq[r] + bq[t];
        K[o] = ak[r] + bk[t];
        V[o] = fmaxf(av[r] + bv[t], 0.0f);
    }
}

// ---------------- Kernel 2: scores = Q K^T / 16 ----------------
// 64x64 C-tile per block, k in chunks of 32, k-major LDS tiles.
__global__ __launch_bounds__(256) void k_scores(
    const float* __restrict__ Q, const float* __restrict__ K, float* __restrict__ att)
{
    __shared__ float Qt[32][68];  // [k][m], 68-pad keeps 16B alignment, conflict-free
    __shared__ float Kt[32][68];  // [k][n]
    const int b = blockIdx.z;
    const int m0 = blockIdx.y * 64, n0 = blockIdx.x * 64;
    const int tid = threadIdx.x;
    const int tx = tid & 15, ty = tid >> 4;     // 16x16 threads, 4x4 microtile
    const float* Qb = Q + (size_t)b * M * DOUT;
    const float* Kb = K + (size_t)b * M * DOUT;

    float acc[4][4];
    #pragma unroll
    for (int i = 0; i < 4; ++i)
        #pragma unroll
        for (int j = 0; j < 4; ++j) acc[i][j] = 0.f;

    for (int k0 = 0; k0 < DOUT; k0 += 32) {
        #pragma unroll
        for (int i = 0; i < 2; ++i) {
            const int c = i * 256 + tid;            // 0..511
            const int row = c >> 3, col = (c & 7) * 4;
            const float4 q  = *(const float4*)&Qb[(size_t)(m0 + row) * DOUT + k0 + col];
            const float4 kk = *(const float4*)&Kb[(size_t)(n0 + row) * DOUT + k0 + col];
            Qt[col + 0][row] = q.x;  Qt[col + 1][row] = q.y;  Qt[col + 2][row] = q.z;  Qt[col + 3][row] = q.w;
            Kt[col + 0][row] = kk.x; Kt[col + 1][row] = kk.y; Kt[col + 2][row] = kk.z; Kt[col + 3][row] = kk.w;
        }
        __syncthreads();
        #pragma unroll
        for (int kk = 0; kk < 32; ++kk) {
            const float4 qv = *(const float4*)&Qt[kk][ty * 4];
            const float4 kv = *(const float4*)&Kt[kk][tx * 4];
            const float qa[4] = {qv.x, qv.y, qv.z, qv.w};
            const float ka[4] = {kv.x, kv.y, kv.z, kv.w};
            #pragma unroll
            for (int i = 0; i < 4; ++i)
                #pragma unroll
                for (int j = 0; j < 4; ++j)
                    acc[i][j] = fmaf(qa[i], ka[j], acc[i][j]);
        }
        __syncthreads();
    }
    float* ab = att + (size_t)b * M * M;
    #pragma unroll
    for (int i = 0; i < 4; ++i) {
        const int m = m0 + ty * 4 + i;
        float4 o;
        o.x = acc[i][0] * SCORE_SCALE;
        o.y = acc[i][1] * SCORE_SCALE;
        o.z = acc[i][2] * SCORE_SCALE;
        o.w = acc[i][3] * SCORE_SCALE;
        *(float4*)&ab[(size_t)m * M + n0 + tx * 4] = o;
    }
}

// ---------------- Kernel 3: in-place row softmax over att ----------------
__global__ __launch_bounds__(256) void k_softmax(float* __restrict__ att)
{
    __shared__ float redm[4], reds[4];
    const size_t row = blockIdx.x;
    float* p = att + row * (size_t)M;
    const int tid = threadIdx.x;
    float4 v0 = ((const float4*)p)[tid];
    float4 v1 = ((const float4*)p)[tid + 256];

    float mx = fmaxf(fmaxf(fmaxf(v0.x, v0.y), fmaxf(v0.z, v0.w)),
                     fmaxf(fmaxf(v1.x, v1.y), fmaxf(v1.z, v1.w)));
    #pragma unroll
    for (int off = 32; off >= 1; off >>= 1) mx = fmaxf(mx, __shfl_xor(mx, off, 64));
    if ((tid & 63) == 0) redm[tid >> 6] = mx;
    __syncthreads();
    mx = fmaxf(fmaxf(redm[0], redm[1]), fmaxf(redm[2], redm[3]));

    v0.x = expf(v0.x - mx); v0.y = expf(v0.y - mx); v0.z = expf(v0.z - mx); v0.w = expf(v0.w - mx);
    v1.x = expf(v1.x - mx); v1.y = expf(v1.y - mx); v1.z = expf(v1.z - mx); v1.w = expf(v1.w - mx);
    float s = (v0.x + v0.y) + (v0.z + v0.w) + (v1.x + v1.y) + (v1.z + v1.w);
    #pragma unroll
    for (int off = 32; off >= 1; off >>= 1) s += __shfl_xor(s, off, 64);
    if ((tid & 63) == 0) reds[tid >> 6] = s;
    __syncthreads();
    s = (reds[0] + reds[1]) + (reds[2] + reds[3]);
    const float inv = 1.0f / s;

    v0.x *= inv; v0.y *= inv; v0.z *= inv; v0.w *= inv;
    v1.x *= inv; v1.y *= inv; v1.z *= inv; v1.w *= inv;
    ((float4*)p)[tid] = v0;
    ((float4*)p)[tid + 256] = v1;
}

// ---------------- Kernel 4: emb = att@V, fused l2norm+residual+l2norm ----------------
// Block = 32 m-rows x full 128 e-cols so the per-row l2norms stay on-chip.
__global__ __launch_bounds__(256) void k_av(
    const float* __restrict__ att, const float* __restrict__ V, float* __restrict__ out)
{
    __shared__ float At[32][36];    // [k(n)][m], padded
    __shared__ float Vs[32][128];   // [k(n)][e] natural k-major; reused as emb tile
    const int b = blockIdx.y;
    const int m0 = blockIdx.x * 32;
    const int tid = threadIdx.x;
    const int tx = tid & 31, ty = tid >> 5;     // 32x8 threads, 4x4 microtile
    const float* ab = att + (size_t)b * M * M;
    const float* Vb = V + (size_t)b * M * DOUT;

    float acc[4][4];
    #pragma unroll
    for (int i = 0; i < 4; ++i)
        #pragma unroll
        for (int j = 0; j < 4; ++j) acc[i][j] = 0.f;

    for (int n0 = 0; n0 < M; n0 += 32) {
        {
            const int row = tid >> 3, col = (tid & 7) * 4;
            const float4 a = *(const float4*)&ab[(size_t)(m0 + row) * M + n0 + col];
            At[col + 0][row] = a.x; At[col + 1][row] = a.y; At[col + 2][row] = a.z; At[col + 3][row] = a.w;
        }
        #pragma unroll
        for (int i = 0; i < 4; ++i) {
            const int c = i * 256 + tid;
            const int row = c >> 5, col = (c & 31) * 4;
            *(float4*)&Vs[row][col] = *(const float4*)&Vb[(size_t)(n0 + row) * DOUT + col];
        }
        __syncthreads();
        #pragma unroll
        for (int kk = 0; kk < 32; ++kk) {
            const float4 a4 = *(const float4*)&At[kk][ty * 4];
            const float4 v4 = *(const float4*)&Vs[kk][tx * 4];
            const float aa[4] = {a4.x, a4.y, a4.z, a4.w};
            const float vv[4] = {v4.x, v4.y, v4.z, v4.w};
            #pragma unroll
            for (int i = 0; i < 4; ++i)
                #pragma unroll
                for (int j = 0; j < 4; ++j)
                    acc[i][j] = fmaf(aa[i], vv[j], acc[i][j]);
        }
        __syncthreads();
    }

    // stage emb tile into Vs (compute loop is done; last sync above protects reuse)
    #pragma unroll
    for (int i = 0; i < 4; ++i)
        #pragma unroll
        for (int j = 0; j < 4; ++j)
            Vs[ty * 4 + i][tx * 4 + j] = acc[i][j];
    __syncthreads();

    const int lane = tid & 63, w = tid >> 6;    // 4 waves, one row each per pass
    for (int r = w; r < 32; r += 4) {
        const float e0 = Vs[r][lane];
        const float e1 = Vs[r][lane + 64];
        float ss = fmaf(e0, e0, e1 * e1);
        #pragma unroll
        for (int off = 32; off >= 1; off >>= 1) ss += __shfl_xor(ss, off, 64);
        const float rs = rsqrtf(fmaxf(ss, 1e-12f));
        const float vv0 = Vb[(size_t)(m0 + r) * DOUT + lane];
        const float vv1 = Vb[(size_t)(m0 + r) * DOUT + lane + 64];
        const float t0 = vv0 + e0 * rs;
        const float t1 = vv1 + e1 * rs;
        float s2 = fmaf(t0, t0, t1 * t1);
        #pragma unroll
        for (int off = 32; off >= 1; off >>= 1) s2 += __shfl_xor(s2, off, 64);
        const float rs2 = rsqrtf(fmaxf(s2, 1e-12f));
        const size_t o = ((size_t)b * M + m0 + r) * DOUT;
        out[o + lane] = t0 * rs2;
        out[o + lane + 64] = t1 * rs2;
    }
}

extern "C" void kernel_launch(void* const* d_in, const int* in_sizes, int n_in,
                              void* d_out, int out_size, void* d_ws, size_t ws_size,
                              hipStream_t stream)
{
    const float* Y  = (const float*)d_in[0];
    const int*   idx = (const int*)d_in[1];
    const float* Wq = (const float*)d_in[2];
    const float* bq = (const float*)d_in[3];
    const float* Wk = (const float*)d_in[4];
    const float* bk = (const float*)d_in[5];
    const float* Wv = (const float*)d_in[6];
    const float* bv = (const float*)d_in[7];

    float* out = (float*)d_out;                       // [B*M*DOUT]
    float* att = out + (size_t)B * M * DOUT;          // [B*M*M] (scores scratch -> final att)

    float* Q = (float*)d_ws;                          // 3 x 8.39 MB in workspace
    float* K = Q + (size_t)B * M * DOUT;
    float* V = K + (size_t)B * M * DOUT;

    k_proj   <<<B * M / 8, 128, 0, stream>>>(Y, idx, Wq, bq, Wk, bk, Wv, bv, Q, K, V);
    k_scores <<<dim3(M / 64, M / 64, B), 256, 0, stream>>>(Q, K, att);
    k_softmax<<<B * M, 256, 0, stream>>>(att);
    k_av     <<<dim3(M / 32, B), 256, 0, stream>>>(att, V, out);
}

// Round 2
// 325.387 us; speedup vs baseline: 1.5277x; 1.5277x over previous
//
#include <hip/hip_runtime.h>
#include <hip/hip_bf16.h>
#include <math.h>

typedef __attribute__((ext_vector_type(8))) short short8;
typedef __attribute__((ext_vector_type(16))) float f32x16;

constexpr int B = 8, N = 4096, M = 2048, DIN = 256, DOUT = 128;
constexpr float SCORE_SCALE = 0.0625f; // 1/sqrt(256)

__device__ __forceinline__ unsigned short f2b(float x) {
    unsigned int u = __builtin_bit_cast(unsigned int, x);
    u += 0x7fffu + ((u >> 16) & 1u);           // RNE
    return (unsigned short)(u >> 16);
}

// ---------------- Kernel 1: gather + QKV projection (bf16 out + f32 V) ----------------
__global__ __launch_bounds__(128) void k_proj(
    const float* __restrict__ Y, const int* __restrict__ idx,
    const float* __restrict__ Wq, const float* __restrict__ bq,
    const float* __restrict__ Wk, const float* __restrict__ bk,
    const float* __restrict__ Wv, const float* __restrict__ bv,
    unsigned short* __restrict__ Qb, unsigned short* __restrict__ Kb,
    unsigned short* __restrict__ Vb, float* __restrict__ Vf)
{
    constexpr int TM = 8;
    __shared__ float g[TM][DIN];
    const int rm0 = blockIdx.x * TM;        // flat row b*M+m
    const int b = rm0 / M;
    const int t = threadIdx.x;              // 0..127 = output column e
    #pragma unroll
    for (int r = 0; r < TM; ++r) {
        const int id = idx[rm0 + r];
        const float2* src = (const float2*)(Y + ((size_t)b * N + id) * DIN);
        ((float2*)g[r])[t] = src[t];
    }
    __syncthreads();

    float aq[TM], ak[TM], av[TM];
    #pragma unroll
    for (int r = 0; r < TM; ++r) { aq[r] = 0.f; ak[r] = 0.f; av[r] = 0.f; }

    for (int d = 0; d < DIN; d += 4) {
        float wq[4], wk[4], wv[4];
        #pragma unroll
        for (int u = 0; u < 4; ++u) {
            wq[u] = Wq[(d + u) * DOUT + t];
            wk[u] = Wk[(d + u) * DOUT + t];
            wv[u] = Wv[(d + u) * DOUT + t];
        }
        #pragma unroll
        for (int r = 0; r < TM; ++r) {
            const float4 gv = *(const float4*)&g[r][d];
            aq[r] = fmaf(gv.x, wq[0], fmaf(gv.y, wq[1], fmaf(gv.z, wq[2], fmaf(gv.w, wq[3], aq[r]))));
            ak[r] = fmaf(gv.x, wk[0], fmaf(gv.y, wk[1], fmaf(gv.z, wk[2], fmaf(gv.w, wk[3], ak[r]))));
            av[r] = fmaf(gv.x, wv[0], fmaf(gv.y, wv[1], fmaf(gv.z, wv[2], fmaf(gv.w, wv[3], av[r]))));
        }
    }
    #pragma unroll
    for (int r = 0; r < TM; ++r) {
        const size_t o = (size_t)(rm0 + r) * DOUT + t;
        const float q = aq[r] + bq[t];
        const float k = ak[r] + bk[t];
        const float v = fmaxf(av[r] + bv[t], 0.0f);
        Qb[o] = f2b(q);
        Kb[o] = f2b(k);
        Vb[o] = f2b(v);
        Vf[o] = v;
    }
}

// ---------------- Kernel 2: fused attention ----------------
// Block: 64 m-rows x full n (16 chunks of 128). 512 threads = 8 waves.
// Pass1: S=QK^T (mfma 32x32x16), row sums of exp(S/16). Pass2: recompute S,
// P=exp*inv_sum -> write att f32 (only HBM cost), P->bf16 LDS -> P@V mfma,
// fused l2norm/residual/l2norm epilogue.
// LDS map (dynamic, 99328 B):
//  Qs @0      64x256B (bf16, swz)
//  Ks @16384  128x256B
//  Ps @49152  64x256B
//  Vt @65536  128x256B (row=e, col=n-chunk)
//  sums @98304 4x64 f32
// XOR swizzle (G4): byte ^= (row&7)<<4  (applied to col-byte within 256B row)
#define SMEM_BYTES 99328

__global__ __launch_bounds__(512) void k_attn(
    const unsigned short* __restrict__ Qb, const unsigned short* __restrict__ Kb,
    const unsigned short* __restrict__ Vb, const float* __restrict__ Vf,
    float* __restrict__ out, float* __restrict__ att)
{
    extern __shared__ char smem[];
    char* Qs = smem;
    char* Ks = smem + 16384;
    char* Ps = smem + 49152;
    char* Vt = smem + 65536;
    float* sums = (float*)(smem + 98304);   // [4][64]

    const int t = threadIdx.x;
    const int l = t & 63, wv = t >> 6;
    const int h = l >> 5;                   // half-wave
    const int b = blockIdx.y;
    const int m0 = blockIdx.x * 64;
    const size_t bM = (size_t)b * M;

    const int mw = wv >> 2, nw = wv & 3;    // scores decomp: 2(m) x 4(n)
    const int amw = wv & 1, aew = wv >> 1;  // AV decomp: 2(m) x 4(e)

    int rowf[16];
    #pragma unroll
    for (int r = 0; r < 16; ++r) rowf[r] = (r & 3) + 8 * (r >> 2) + 4 * h;

    // ---- stage Q (once) ----
    {
        const int row = t >> 3, ce = (t & 7) * 16;  // elem col
        const uint4* src = (const uint4*)(Qb + (bM + m0 + row) * 128 + ce);
        const uint4 q0 = src[0], q1 = src[1];
        *(uint4*)(Qs + row * 256 + ((ce * 2)      ^ ((row & 7) << 4))) = q0;
        *(uint4*)(Qs + row * 256 + ((ce * 2 + 16) ^ ((row & 7) << 4))) = q1;
    }

    const int krow = t >> 2, kce = (t & 3) * 32;    // K staging: 4 thr/row
    const int vrow = t & 127, veb = (t >> 7) * 32;  // V staging: row=n, 32 e
    const int arow = mw * 32 + (l & 31);            // Q row (A frag)
    const int brow = nw * 32 + (l & 31);            // K row (B frag)
    const int kb0 = h * 16;                         // byte offset within 32B k-chunk

    uint4 kreg[4], vreg[4];
    {
        const uint4* src = (const uint4*)(Kb + (bM + krow) * 128 + kce);
        #pragma unroll
        for (int u = 0; u < 4; ++u) kreg[u] = src[u];
    }

    float sum_part[16];
    #pragma unroll
    for (int r = 0; r < 16; ++r) sum_part[r] = 0.f;

    // ---------------- pass 1 ----------------
    for (int c = 0; c < 16; ++c) {
        __syncthreads();
        #pragma unroll
        for (int u = 0; u < 4; ++u)
            *(uint4*)(Ks + krow * 256 + ((kce * 2 + u * 16) ^ ((krow & 7) << 4))) = kreg[u];
        __syncthreads();
        if (c < 15) {
            const uint4* src = (const uint4*)(Kb + (bM + (c + 1) * 128 + krow) * 128 + kce);
            #pragma unroll
            for (int u = 0; u < 4; ++u) kreg[u] = src[u];
        }
        f32x16 acc;
        #pragma unroll
        for (int i = 0; i < 16; ++i) acc[i] = 0.f;
        #pragma unroll
        for (int kc = 0; kc < 8; ++kc) {
            const short8 a  = *(const short8*)(Qs + arow * 256 + ((kc * 32 + kb0) ^ ((arow & 7) << 4)));
            const short8 bb = *(const short8*)(Ks + brow * 256 + ((kc * 32 + kb0) ^ ((brow & 7) << 4)));
            acc = __builtin_amdgcn_mfma_f32_32x32x16_bf16(a, bb, acc, 0, 0, 0);
        }
        #pragma unroll
        for (int r = 0; r < 16; ++r)
            sum_part[r] += __expf(acc[r] * SCORE_SCALE);
    }

    // ---- row sums: reduce over 32 lanes (cols), combine 4 nw waves ----
    #pragma unroll
    for (int r = 0; r < 16; ++r) {
        float s = sum_part[r];
        #pragma unroll
        for (int off = 1; off <= 16; off <<= 1) s += __shfl_xor(s, off, 64);
        sum_part[r] = s;
    }
    if ((l & 31) == 0) {
        #pragma unroll
        for (int r = 0; r < 16; ++r) sums[nw * 64 + mw * 32 + rowf[r]] = sum_part[r];
    }
    __syncthreads();
    float inv_s[16];
    #pragma unroll
    for (int r = 0; r < 16; ++r) {
        const int rw = mw * 32 + rowf[r];
        inv_s[r] = 1.0f / (sums[rw] + sums[64 + rw] + sums[128 + rw] + sums[192 + rw]);
    }

    // ---------------- pass 2 ----------------
    {
        const uint4* sk = (const uint4*)(Kb + (bM + krow) * 128 + kce);
        #pragma unroll
        for (int u = 0; u < 4; ++u) kreg[u] = sk[u];
        const uint4* sv = (const uint4*)(Vb + (bM + vrow) * 128 + veb);
        #pragma unroll
        for (int u = 0; u < 4; ++u) vreg[u] = sv[u];
    }
    f32x16 accv;
    #pragma unroll
    for (int i = 0; i < 16; ++i) accv[i] = 0.f;

    float* attb = att + bM * M;
    const int parow = amw * 32 + (l & 31);
    const int vbrow = aew * 32 + (l & 31);

    for (int c = 0; c < 16; ++c) {
        __syncthreads();
        #pragma unroll
        for (int u = 0; u < 4; ++u)
            *(uint4*)(Ks + krow * 256 + ((kce * 2 + u * 16) ^ ((krow & 7) << 4))) = kreg[u];
        #pragma unroll
        for (int u = 0; u < 4; ++u) {               // V transpose write
            union { uint4 q; unsigned short us[8]; } cv; cv.q = vreg[u];
            #pragma unroll
            for (int j = 0; j < 8; ++j) {
                const int e = veb + u * 8 + j;
                *(unsigned short*)(Vt + e * 256 + ((vrow * 2) ^ ((e & 7) << 4))) = cv.us[j];
            }
        }
        __syncthreads();
        if (c < 15) {
            const uint4* sk = (const uint4*)(Kb + (bM + (c + 1) * 128 + krow) * 128 + kce);
            #pragma unroll
            for (int u = 0; u < 4; ++u) kreg[u] = sk[u];
            const uint4* sv = (const uint4*)(Vb + (bM + (c + 1) * 128 + vrow) * 128 + veb);
            #pragma unroll
            for (int u = 0; u < 4; ++u) vreg[u] = sv[u];
        }
        // scores (identical sequence to pass1 -> identical bits)
        f32x16 acc;
        #pragma unroll
        for (int i = 0; i < 16; ++i) acc[i] = 0.f;
        #pragma unroll
        for (int kc = 0; kc < 8; ++kc) {
            const short8 a  = *(const short8*)(Qs + arow * 256 + ((kc * 32 + kb0) ^ ((arow & 7) << 4)));
            const short8 bb = *(const short8*)(Ks + brow * 256 + ((kc * 32 + kb0) ^ ((brow & 7) << 4)));
            acc = __builtin_amdgcn_mfma_f32_32x32x16_bf16(a, bb, acc, 0, 0, 0);
        }
        const int ncol = c * 128 + nw * 32 + (l & 31);
        #pragma unroll
        for (int r = 0; r < 16; ++r) {
            const float p = __expf(acc[r] * SCORE_SCALE) * inv_s[r];
            const int prow = mw * 32 + rowf[r];
            attb[(size_t)(m0 + prow) * M + ncol] = p;
            *(unsigned short*)(Ps + prow * 256 + (((nw * 32 + (l & 31)) * 2) ^ ((prow & 7) << 4))) = f2b(p);
        }
        __syncthreads();
        // AV: P[64 x 128chunk] @ V[128chunk x 128e]
        #pragma unroll
        for (int kc = 0; kc < 8; ++kc) {
            const short8 pa = *(const short8*)(Ps + parow * 256 + ((kc * 32 + kb0) ^ ((parow & 7) << 4)));
            const short8 vb = *(const short8*)(Vt + vbrow * 256 + ((kc * 32 + kb0) ^ ((vbrow & 7) << 4)));
            accv = __builtin_amdgcn_mfma_f32_32x32x16_bf16(pa, vb, accv, 0, 0, 0);
        }
    }

    // ---------------- epilogue: l2norm -> +V -> l2norm ----------------
    __syncthreads();
    float* Es = (float*)smem;                       // [64][129] f32 (reuses Qs/Ks)
    #pragma unroll
    for (int r = 0; r < 16; ++r)
        Es[(amw * 32 + rowf[r]) * 129 + aew * 32 + (l & 31)] = accv[r];
    __syncthreads();
    #pragma unroll
    for (int rr = 0; rr < 8; ++rr) {
        const int row = wv * 8 + rr;
        const float e0 = Es[row * 129 + l];
        const float e1 = Es[row * 129 + l + 64];
        float ss = fmaf(e0, e0, e1 * e1);
        #pragma unroll
        for (int off = 32; off >= 1; off >>= 1) ss += __shfl_xor(ss, off, 64);
        const float rs = rsqrtf(fmaxf(ss, 1e-12f));
        const float v0 = Vf[(bM + m0 + row) * 128 + l];
        const float v1 = Vf[(bM + m0 + row) * 128 + l + 64];
        const float t0 = v0 + e0 * rs, t1 = v1 + e1 * rs;
        float s2 = fmaf(t0, t0, t1 * t1);
        #pragma unroll
        for (int off = 32; off >= 1; off >>= 1) s2 += __shfl_xor(s2, off, 64);
        const float rs2 = rsqrtf(fmaxf(s2, 1e-12f));
        const size_t o = (bM + m0 + row) * 128;
        out[o + l] = t0 * rs2;
        out[o + l + 64] = t1 * rs2;
    }
}

extern "C" void kernel_launch(void* const* d_in, const int* in_sizes, int n_in,
                              void* d_out, int out_size, void* d_ws, size_t ws_size,
                              hipStream_t stream)
{
    const float* Y  = (const float*)d_in[0];
    const int*  idx = (const int*)d_in[1];
    const float* Wq = (const float*)d_in[2];
    const float* bq = (const float*)d_in[3];
    const float* Wk = (const float*)d_in[4];
    const float* bk = (const float*)d_in[5];
    const float* Wv = (const float*)d_in[6];
    const float* bv = (const float*)d_in[7];

    float* out = (float*)d_out;                     // [B*M*128]
    float* att = out + (size_t)B * M * DOUT;        // [B*M*M]

    unsigned short* Qb = (unsigned short*)d_ws;     // bf16, 4 MB each
    unsigned short* Kb = Qb + (size_t)B * M * DOUT;
    unsigned short* Vb = Kb + (size_t)B * M * DOUT;
    float*          Vf = (float*)(Vb + (size_t)B * M * DOUT);

    hipFuncSetAttribute((const void*)k_attn, hipFuncAttributeMaxDynamicSharedMemorySize, SMEM_BYTES);

    k_proj<<<B * M / 8, 128, 0, stream>>>(Y, idx, Wq, bq, Wk, bk, Wv, bv, Qb, Kb, Vb, Vf);
    k_attn<<<dim3(M / 64, B), 512, SMEM_BYTES, stream>>>(Qb, Kb, Vb, Vf, out, att);
}

// Round 4
// 307.147 us; speedup vs baseline: 1.6184x; 1.0594x over previous
//
#include <hip/hip_runtime.h>
#include <hip/hip_bf16.h>
#include <math.h>

typedef __attribute__((ext_vector_type(8))) short short8;
typedef __attribute__((ext_vector_type(16))) float f32x16;

constexpr int B = 8, N = 4096, M = 2048, DIN = 256, DOUT = 128;
constexpr float SCORE_SCALE = 0.0625f; // 1/sqrt(256)

__device__ __forceinline__ unsigned short f2b(float x) {
    unsigned int u = __builtin_bit_cast(unsigned int, x);
    u += 0x7fffu + ((u >> 16) & 1u);           // RNE
    return (unsigned short)(u >> 16);
}

// ---------------- Kernel 1: gather + QKV projection ----------------
// 32 rows/block, 512 threads: e = t&127, quarter q = t>>7 owns rows q*8..q*8+7.
// Outputs: Qb,Kb bf16 [b][n][k]; Vbt bf16 [b][e][n] (transposed for PV B-frags);
// Vf f32 [b][n][e] for the exact epilogue.
__global__ __launch_bounds__(512) void k_proj(
    const float* __restrict__ Y, const int* __restrict__ idx,
    const float* __restrict__ Wq, const float* __restrict__ bq,
    const float* __restrict__ Wk, const float* __restrict__ bk,
    const float* __restrict__ Wv, const float* __restrict__ bv,
    unsigned short* __restrict__ Qb, unsigned short* __restrict__ Kb,
    unsigned short* __restrict__ Vbt, float* __restrict__ Vf)
{
    __shared__ float g[32][DIN];
    const int b = blockIdx.x;
    const int m0 = blockIdx.y * 32;
    const int t = threadIdx.x;
    const int e = t & 127, q = t >> 7;

    // gather: 16 threads per row, 4x float4 each, coalesced
    {
        const int gr = t >> 4, gc = t & 15;
        const int id = idx[b * M + m0 + gr];
        const float4* src = (const float4*)(Y + ((size_t)b * N + id) * DIN);
        float4* dst = (float4*)g[gr];
        #pragma unroll
        for (int j = 0; j < 4; ++j) dst[gc + 16 * j] = src[gc + 16 * j];
    }
    __syncthreads();

    float aq[8], ak[8], av[8];
    #pragma unroll
    for (int r = 0; r < 8; ++r) { aq[r] = 0.f; ak[r] = 0.f; av[r] = 0.f; }

    for (int d = 0; d < DIN; d += 4) {
        float wq[4], wk[4], wv[4];
        #pragma unroll
        for (int u = 0; u < 4; ++u) {
            wq[u] = Wq[(d + u) * DOUT + e];
            wk[u] = Wk[(d + u) * DOUT + e];
            wv[u] = Wv[(d + u) * DOUT + e];
        }
        #pragma unroll
        for (int r = 0; r < 8; ++r) {
            const float4 gv = *(const float4*)&g[q * 8 + r][d];
            aq[r] = fmaf(gv.x, wq[0], fmaf(gv.y, wq[1], fmaf(gv.z, wq[2], fmaf(gv.w, wq[3], aq[r]))));
            ak[r] = fmaf(gv.x, wk[0], fmaf(gv.y, wk[1], fmaf(gv.z, wk[2], fmaf(gv.w, wk[3], ak[r]))));
            av[r] = fmaf(gv.x, wv[0], fmaf(gv.y, wv[1], fmaf(gv.z, wv[2], fmaf(gv.w, wv[3], av[r]))));
        }
    }

    const float bqe = bq[e], bke = bk[e], bve = bv[e];
    unsigned short vus[8];
    #pragma unroll
    for (int r = 0; r < 8; ++r) {
        const size_t o = ((size_t)b * M + m0 + q * 8 + r) * DOUT + e;
        const float qv = aq[r] + bqe;
        const float kv = ak[r] + bke;
        const float vv = fmaxf(av[r] + bve, 0.0f);
        Qb[o] = f2b(qv);
        Kb[o] = f2b(kv);
        Vf[o] = vv;
        vus[r] = f2b(vv);
    }
    // transposed V: Vbt[b][e][n], one 16B store of this thread's 8 n-values
    *(uint4*)(Vbt + ((size_t)b * DOUT + e) * M + m0 + q * 8) = *(uint4*)vus;
}

// ---------------- Kernel 2: fused attention ----------------
// Block: 32 m-rows, 256 threads = 4 waves (wave = nw col-group / ew e-group).
// Q fragments in registers. K/V B-fragments loaded straight from global
// (row-major [n][k] / [e][n] give the A-frag access pattern: 16B/lane).
// Pass1: S=QK^T, accumulate row sums of exp. Pass2: recompute S, p=exp*inv,
// nontemporal att store, p->bf16 via swizzled LDS, PV mfma, fused epilogue.
__global__ __launch_bounds__(256) void k_attn(
    const unsigned short* __restrict__ Qb, const unsigned short* __restrict__ Kb,
    const unsigned short* __restrict__ Vbt, const float* __restrict__ Vf,
    float* __restrict__ out, float* __restrict__ att)
{
    __shared__ char Ps[32 * 256];       // bf16 [32 m][128 n], XOR-swizzled
    __shared__ float Es[32][132];       // f32 emb tile for epilogue
    __shared__ float sums[4][32];

    const int t = threadIdx.x;
    const int l = t & 63, wv = t >> 6;
    const int h = l >> 5, ln = l & 31;
    const int b = blockIdx.x;
    const int m0 = blockIdx.y * 32;
    const size_t bM = (size_t)b * M;
    const int nw = wv;                  // pass1: n col-group
    const int ew = wv;                  // pass2: e col-group

    int rowf[16];
    #pragma unroll
    for (int r = 0; r < 16; ++r) rowf[r] = (r & 3) + 8 * (r >> 2) + 4 * h;

    // ---- Q fragments in registers (reused all chunks, both passes) ----
    short8 qf[8];
    {
        const unsigned short* qrow = Qb + (bM + m0 + ln) * DOUT + h * 8;
        #pragma unroll
        for (int kc = 0; kc < 8; ++kc) qf[kc] = *(const short8*)(qrow + kc * 16);
    }

    const unsigned short* Kbase = Kb + (bM + nw * 32 + ln) * DOUT + h * 8;
    const unsigned short* Vbase = Vbt + ((size_t)b * DOUT + ew * 32 + ln) * M + h * 8;

    // ---------------- pass 1: row sums ----------------
    short8 kf0[8], kf1[8];
    #pragma unroll
    for (int kc = 0; kc < 8; ++kc) kf0[kc] = *(const short8*)(Kbase + kc * 16);
    float sum_part[16];
    #pragma unroll
    for (int r = 0; r < 16; ++r) sum_part[r] = 0.f;

    #pragma unroll 1
    for (int cp = 0; cp < 8; ++cp) {
        const int c0 = cp * 2;
        #pragma unroll
        for (int kc = 0; kc < 8; ++kc)
            kf1[kc] = *(const short8*)(Kbase + (size_t)(c0 + 1) * 128 * DOUT + kc * 16);
        f32x16 acc;
        #pragma unroll
        for (int i = 0; i < 16; ++i) acc[i] = 0.f;
        #pragma unroll
        for (int kc = 0; kc < 8; ++kc)
            acc = __builtin_amdgcn_mfma_f32_32x32x16_bf16(qf[kc], kf0[kc], acc, 0, 0, 0);
        #pragma unroll
        for (int r = 0; r < 16; ++r) sum_part[r] += __expf(acc[r] * SCORE_SCALE);
        if (cp < 7) {
            #pragma unroll
            for (int kc = 0; kc < 8; ++kc)
                kf0[kc] = *(const short8*)(Kbase + (size_t)(c0 + 2) * 128 * DOUT + kc * 16);
        }
        #pragma unroll
        for (int i = 0; i < 16; ++i) acc[i] = 0.f;
        #pragma unroll
        for (int kc = 0; kc < 8; ++kc)
            acc = __builtin_amdgcn_mfma_f32_32x32x16_bf16(qf[kc], kf1[kc], acc, 0, 0, 0);
        #pragma unroll
        for (int r = 0; r < 16; ++r) sum_part[r] += __expf(acc[r] * SCORE_SCALE);
    }

    // reduce over the 32 n-lanes, combine the 4 nw waves via LDS
    #pragma unroll
    for (int r = 0; r < 16; ++r) {
        float s = sum_part[r];
        #pragma unroll
        for (int off = 1; off <= 16; off <<= 1) s += __shfl_xor(s, off, 64);
        sum_part[r] = s;
    }
    if (ln == 0) {
        #pragma unroll
        for (int r = 0; r < 16; ++r) sums[nw][rowf[r]] = sum_part[r];
    }
    __syncthreads();
    float inv_s[16];
    #pragma unroll
    for (int r = 0; r < 16; ++r) {
        const int rw = rowf[r];
        inv_s[r] = 1.0f / (sums[0][rw] + sums[1][rw] + sums[2][rw] + sums[3][rw]);
    }

    // ---------------- pass 2: att + PV + epilogue ----------------
    f32x16 accv;
    #pragma unroll
    for (int i = 0; i < 16; ++i) accv[i] = 0.f;
    float* attb = att + bM * M;

    auto pv_phase = [&](short8 (&cur)[8], short8 (&nxt)[8], int c, bool pf) {
        short8 vf[8];
        #pragma unroll
        for (int kc = 0; kc < 8; ++kc)
            vf[kc] = *(const short8*)(Vbase + (size_t)c * 128 + kc * 16);
        f32x16 acc;
        #pragma unroll
        for (int i = 0; i < 16; ++i) acc[i] = 0.f;
        #pragma unroll
        for (int kc = 0; kc < 8; ++kc)
            acc = __builtin_amdgcn_mfma_f32_32x32x16_bf16(qf[kc], cur[kc], acc, 0, 0, 0);
        if (pf) {
            #pragma unroll
            for (int kc = 0; kc < 8; ++kc)
                nxt[kc] = *(const short8*)(Kbase + (size_t)(c + 1) * 128 * DOUT + kc * 16);
        }
        const int ncol = c * 128 + nw * 32 + ln;
        #pragma unroll
        for (int r = 0; r < 16; ++r) {
            const float p = __expf(acc[r] * SCORE_SCALE) * inv_s[r];
            const int prow = rowf[r];
            __builtin_nontemporal_store(p, &attb[(size_t)(m0 + prow) * M + ncol]);
            *(unsigned short*)(Ps + prow * 256 + (((nw * 32 + ln) * 2) ^ ((prow & 7) << 4))) = f2b(p);
        }
        __syncthreads();
        #pragma unroll
        for (int kc = 0; kc < 8; ++kc) {
            const short8 pa = *(const short8*)(Ps + ln * 256 + ((kc * 32 + h * 16) ^ ((ln & 7) << 4)));
            accv = __builtin_amdgcn_mfma_f32_32x32x16_bf16(pa, vf[kc], accv, 0, 0, 0);
        }
        __syncthreads();
    };

    #pragma unroll
    for (int kc = 0; kc < 8; ++kc) kf0[kc] = *(const short8*)(Kbase + kc * 16);
    #pragma unroll 1
    for (int cp = 0; cp < 8; ++cp) {
        pv_phase(kf0, kf1, cp * 2, true);
        pv_phase(kf1, kf0, cp * 2 + 1, cp < 7);
    }

    // epilogue: l2norm(emb) -> +V -> l2norm
    #pragma unroll
    for (int r = 0; r < 16; ++r)
        Es[rowf[r]][ew * 32 + ln] = accv[r];
    __syncthreads();
    #pragma unroll
    for (int rr = 0; rr < 8; ++rr) {
        const int row = wv * 8 + rr;
        const float e0 = Es[row][l];
        const float e1 = Es[row][l + 64];
        float ss = fmaf(e0, e0, e1 * e1);
        #pragma unroll
        for (int off = 32; off >= 1; off >>= 1) ss += __shfl_xor(ss, off, 64);
        const float rs = rsqrtf(fmaxf(ss, 1e-12f));
        const float v0 = Vf[(bM + m0 + row) * DOUT + l];
        const float v1 = Vf[(bM + m0 + row) * DOUT + l + 64];
        const float t0 = v0 + e0 * rs, t1 = v1 + e1 * rs;
        float s2 = fmaf(t0, t0, t1 * t1);
        #pragma unroll
        for (int off = 32; off >= 1; off >>= 1) s2 += __shfl_xor(s2, off, 64);
        const float rs2 = rsqrtf(fmaxf(s2, 1e-12f));
        const size_t o = (bM + m0 + row) * DOUT;
        out[o + l] = t0 * rs2;
        out[o + l + 64] = t1 * rs2;
    }
}

extern "C" void kernel_launch(void* const* d_in, const int* in_sizes, int n_in,
                              void* d_out, int out_size, void* d_ws, size_t ws_size,
                              hipStream_t stream)
{
    const float* Y  = (const float*)d_in[0];
    const int*  idx = (const int*)d_in[1];
    const float* Wq = (const float*)d_in[2];
    const float* bq = (const float*)d_in[3];
    const float* Wk = (const float*)d_in[4];
    const float* bk = (const float*)d_in[5];
    const float* Wv = (const float*)d_in[6];
    const float* bv = (const float*)d_in[7];

    float* out = (float*)d_out;                     // [B*M*128]
    float* att = out + (size_t)B * M * DOUT;        // [B*M*M]

    unsigned short* Qb  = (unsigned short*)d_ws;    // 4 MB each bf16 buffer
    unsigned short* Kb  = Qb + (size_t)B * M * DOUT;
    unsigned short* Vbt = Kb + (size_t)B * M * DOUT;
    float*          Vf  = (float*)(Vbt + (size_t)B * M * DOUT);

    // grid (8 batches, 64 m-tiles): linear id % 8 == batch -> XCD-pinned L2
    k_proj<<<dim3(8, M / 32), 512, 0, stream>>>(Y, idx, Wq, bq, Wk, bk, Wv, bv, Qb, Kb, Vbt, Vf);
    k_attn<<<dim3(8, M / 32), 256, 0, stream>>>(Qb, Kb, Vbt, Vf, out, att);
}